// Round 5
// baseline (28718.747 us; speedup 1.0000x reference)
//
#include <hip/hip_runtime.h>
#include <hip/hip_bf16.h>
#include <stdint.h>

#define NWG 256
typedef unsigned long long u64;

typedef __attribute__((ext_vector_type(8))) short bf16x8;
typedef __attribute__((ext_vector_type(4))) float f32x4;

__device__ __forceinline__ unsigned f2bfu(float f) {
    unsigned u = __float_as_uint(f);
    return (u + 0x7fffu + ((u >> 16) & 1u)) >> 16;   // rne bf16, low 16 bits
}
__device__ __forceinline__ short f2bf(float f) { return (short)f2bfu(f); }

__device__ __forceinline__ void gload16(const void* g, void* l) {
    __builtin_amdgcn_global_load_lds(
        (const __attribute__((address_space(1))) void*)g,
        (__attribute__((address_space(3))) void*)l, 16, 0, 0);
}

__device__ __forceinline__ unsigned aldu(const unsigned* p) {
    return __hip_atomic_load(p, __ATOMIC_RELAXED, __HIP_MEMORY_SCOPE_AGENT);
}
__device__ __forceinline__ void astu(unsigned* p, unsigned v) {
    __hip_atomic_store(p, v, __ATOMIC_RELAXED, __HIP_MEMORY_SCOPE_AGENT);
}
__device__ __forceinline__ unsigned packh(unsigned tag, float f) {
    return (tag << 16) | f2bfu(f);
}
__device__ __forceinline__ float unpackh(unsigned v) {
    return __uint_as_float(v << 16);
}

// ---------------- P1: misc prep (grid-stride) ----------------
__global__ void prep_all(const int* __restrict__ x, const int* __restrict__ Vg, const int* __restrict__ Jg,
                         const float* __restrict__ emb, const float* __restrict__ embV, const float* __restrict__ embJ,
                         const float* __restrict__ Wih_e,
                         const float* __restrict__ Wih_d, const float* __restrict__ Whh_d,
                         float* __restrict__ out,
                         short* __restrict__ Abf, short* __restrict__ Wbf,
                         float* __restrict__ wsum,
                         unsigned* __restrict__ bufE, unsigned* __restrict__ bufD)
{
    const size_t i0 = (size_t)blockIdx.x * blockDim.x + threadIdx.x;
    const size_t str = (size_t)gridDim.x * blockDim.x;
    for (size_t i = i0; i < (size_t)4096 * 1024; i += str) {
        int t = (int)(i >> 10), j = (int)(i & 1023);
        float v = emb[(size_t)x[t] * 1024 + j];
        out[4195328 + i] = v;
        Abf[i] = f2bf(v);
    }
    for (size_t i = i0; i < (size_t)8192 * 1024; i += str) Wbf[i] = f2bf(Wih_e[i]);
    for (size_t i = i0; i < (size_t)4096 * 1024; i += str) wsum[i] = Wih_d[i] + Whh_d[i];
    for (size_t i = i0; i < 1024; i += str) {
        out[1024 + i] = emb[1 * 1024 + i];                        // recon row 0    = emb[B_IDX]
        out[1024 + (size_t)4095 * 1024 + i] = emb[23 * 1024 + i]; // recon row 4095 = emb[X_IDX]
    }
    // encoder h buffers [3][2048] u32: zeros (h_0 = bf16 0.0 tag 0; bufs 1,2 polled for tags 1,2)
    for (size_t i = i0; i < 6144; i += str) bufE[i] = 0u;
    // decoder h buffers [3][1024] u32: buf0 = latent_cat slots; buf1/2 zeros (tag 0, polled for 1,2)
    for (size_t i = i0; i < 3072; i += str) {
        unsigned v = 0u;
        if (i < 1024) {
            if (i < 128)      v = packh(0u, embV[(size_t)Vg[0] * 128 + i]);
            else if (i < 896) v = 0xFFFF0000u;   // latent sentinel (tag != 0)
            else              v = packh(0u, embJ[(size_t)Jg[0] * 128 + (i - 896)]);
        }
        bufD[i] = v;
    }
    for (size_t i = i0; i < 128; i += str) {
        out[i]       = embV[(size_t)Vg[0] * 128 + i];
        out[896 + i] = embJ[(size_t)Jg[0] * 128 + i];
    }
}

// ---------------- P2: pg = W_ih_dec @ prev0 + b_dec ----------------
__global__ void prep_pg(const float* __restrict__ Wih_d, const float* __restrict__ emb,
                        const float* __restrict__ bih_d, const float* __restrict__ bhh_d,
                        float* __restrict__ pg)
{
    const int lane = threadIdx.x & 63, wv = threadIdx.x >> 6;
    const float* prev0 = emb + 23 * 1024;
    for (int rr = 0; rr < 16; rr++) {
        int row = blockIdx.x * 64 + wv * 16 + rr;
        float s = 0.f;
        #pragma unroll
        for (int q = 0; q < 16; q++) {
            int k = lane + q * 64;
            s += Wih_d[(size_t)row * 1024 + k] * prev0[k];
        }
        for (int o = 32; o; o >>= 1) s += __shfl_xor(s, o, 64);
        if (lane == 0) pg[row] = s + bih_d[row] + bhh_d[row];
    }
}

// ---------------- P3: Gx = embedded @ W_ih_enc^T + (bih+bhh) (bf16 MFMA) ----------------
__launch_bounds__(256, 2)
__global__ void gemm_xgates(const short* __restrict__ A,   // [4096][1024] bf16 bits
                            const short* __restrict__ B,   // [8192][1024] bf16 bits
                            const float* __restrict__ bih, const float* __restrict__ bhh,
                            float* __restrict__ C)         // [4096][8192]
{
    __shared__ short lA[128 * 32];
    __shared__ short lB[128 * 32];
    const int bid = blockIdx.x;
    const int mb = bid >> 6;
    const int nb = bid & 63;
    const int tid = threadIdx.x, lane = tid & 63, wv = tid >> 6;
    const int wr = wv >> 1, wc = wv & 1;
    const int Mbase = mb * 128, Nbase = nb * 128;
    f32x4 acc[4][4] = {};

    for (int kt = 0; kt < 32; kt++) {
        __syncthreads();
        const int k0b = kt * 64;
        #pragma unroll
        for (int c = 0; c < 2; c++) {
            int f = tid * 16 + c * 4096;
            int row = f >> 6, kb = f & 63;
            const char* ga = (const char*)A + (size_t)(Mbase + row) * 2048 + k0b + kb;
            const char* gb = (const char*)B + (size_t)(Nbase + row) * 2048 + k0b + kb;
            gload16(ga, (char*)lA + wv * 1024 + c * 4096);
            gload16(gb, (char*)lB + wv * 1024 + c * 4096);
        }
        asm volatile("s_waitcnt vmcnt(0)" ::: "memory");
        __syncthreads();
        bf16x8 af[4], bf[4];
        #pragma unroll
        for (int i = 0; i < 4; i++) {
            af[i] = *(const bf16x8*)&lA[(wr * 64 + i * 16 + (lane & 15)) * 32 + (lane >> 4) * 8];
            bf[i] = *(const bf16x8*)&lB[(wc * 64 + i * 16 + (lane & 15)) * 32 + (lane >> 4) * 8];
        }
        #pragma unroll
        for (int i = 0; i < 4; i++)
            #pragma unroll
            for (int j = 0; j < 4; j++)
                acc[i][j] = __builtin_amdgcn_mfma_f32_16x16x32_bf16(af[i], bf[j], acc[i][j], 0, 0, 0);
    }
    #pragma unroll
    for (int i = 0; i < 4; i++) {
        #pragma unroll
        for (int j = 0; j < 4; j++) {
            int col = Nbase + wc * 64 + j * 16 + (lane & 15);
            float bv = bih[col] + bhh[col];
            #pragma unroll
            for (int r = 0; r < 4; r++) {
                int row = Mbase + wr * 64 + i * 16 + (lane >> 4) * 4 + r;
                C[(size_t)row * 8192 + col] = acc[i][j][r] + bv;
            }
        }
    }
}

// ---------------- P4: persistent sequential LSTM ----------------
// 512 thr (8 waves). bf16+tag16 u32 exchange; Gx staged in 64-step LDS windows;
// double-buffered hl/red -> 2 barriers per step.
__launch_bounds__(512, 2)
__global__ void rnn_seq(const float* __restrict__ Whh_e,   // [8192][2048]
                        const float* __restrict__ Wls,     // [768][2048]
                        const float* __restrict__ bls,     // [768]
                        const float* __restrict__ Whh_d,   // [4096][1024]
                        const float* __restrict__ Gx,      // [4096][8192]
                        const float* __restrict__ wsum,    // [4096][1024]
                        const float* __restrict__ bih_d, const float* __restrict__ bhh_d,
                        const float* __restrict__ pg,      // [4096]
                        unsigned* __restrict__ bufE,       // [3][2048] tagged bf16 h (enc)
                        unsigned* __restrict__ bufD,       // [3][1024] tagged bf16 h (dec)
                        float* __restrict__ out)
{
    const int w = blockIdx.x;
    const int tid = threadIdx.x;
    const int lane = tid & 63, wv = tid >> 6;       // 8 waves
    __shared__ float hl[2][2048];
    __shared__ float hlG[2][2048];                  // 2 windows x 64 steps x 32 gate-x-terms
    __shared__ float red[2][32];
    __shared__ float cst[8];

    // ---- encoder weights: wave wv owns gate-rows {4wv..4wv+3} of this WG's 32 rows.
    //      Row r: gate = r>>3, h-slot = r&7 -> global row (r>>3)*2048 + 8w + (r&7).
    //      Lane owns k = lane + 64*j.
    float we[128];
    #pragma unroll
    for (int rr = 0; rr < 4; rr++) {
        int r = wv * 4 + rr;
        const float* src = Whh_e + (size_t)((r >> 3) * 2048 + 8 * w + (r & 7)) * 2048 + lane;
        #pragma unroll
        for (int j = 0; j < 32; j++) we[rr * 32 + j] = src[64 * j];
    }
    if (tid < 8) cst[tid] = 0.f;
    __syncthreads();

    // refill source pieces (uniform per thread): step-offset = tid>>3, gate = (tid&7)>>1, half = tid&1
    const size_t gxsrc_off = ((size_t)((tid & 7) >> 1)) * 2048 + 8 * w + (tid & 1) * 4;

    // ================= encoder: 4096 steps =================
    #pragma unroll 1
    for (int t = 0; t < 4096; t++) {
        // window refill: once per 64 steps, bulk global->LDS (drains inside the poll's vmcnt)
        if ((t & 63) == 0) {
            int buf = (t >> 6) & 1;
            const float* src = Gx + (size_t)(t + (tid >> 3)) * 8192 + gxsrc_off;
            gload16(src, (char*)hlG + buf * 8192 + wv * 1024);
        }

        // poll own chunk: lane owns 4 consecutive tagged u32 (16 B)
        const unsigned tg = (unsigned)t;
        const unsigned* p = bufE + (size_t)(t % 3) * 2048 + wv * 256 + 4 * lane;
        unsigned a0 = aldu(p), a1 = aldu(p + 1), a2 = aldu(p + 2), a3 = aldu(p + 3);
        for (;;) {
            bool ok = ((a0 >> 16) == tg) & ((a1 >> 16) == tg)
                    & ((a2 >> 16) == tg) & ((a3 >> 16) == tg);
            if (__builtin_expect(__all(ok), 1)) break;
            a0 = aldu(p); a1 = aldu(p + 1); a2 = aldu(p + 2); a3 = aldu(p + 3);
        }
        float4 hv = { unpackh(a0), unpackh(a1), unpackh(a2), unpackh(a3) };
        *(float4*)&hl[t & 1][wv * 256 + 4 * lane] = hv;
        __syncthreads();

        float s0 = 0.f, s1 = 0.f, s2 = 0.f, s3 = 0.f;
        const float* hp = hl[t & 1];
        #pragma unroll
        for (int j = 0; j < 32; j++) {
            float h = hp[lane + 64 * j];
            s0 += we[j] * h;
            s1 += we[32 + j] * h;
            s2 += we[64 + j] * h;
            s3 += we[96 + j] * h;
        }
        #pragma unroll
        for (int o = 32; o; o >>= 1) {
            s0 += __shfl_xor(s0, o, 64); s1 += __shfl_xor(s1, o, 64);
            s2 += __shfl_xor(s2, o, 64); s3 += __shfl_xor(s3, o, 64);
        }
        if (lane == 0) {
            red[t & 1][wv * 4]     = s0; red[t & 1][wv * 4 + 1] = s1;
            red[t & 1][wv * 4 + 2] = s2; red[t & 1][wv * 4 + 3] = s3;
        }
        __syncthreads();

        if (tid < 32) {
            float g = red[t & 1][tid] + hlG[(t >> 6) & 1][(t & 63) * 32 + tid];
            float gi = __shfl(g, (tid & 7), 64);
            float gf = __shfl(g, (tid & 7) + 8, 64);
            float gg = __shfl(g, (tid & 7) + 16, 64);
            float go = __shfl(g, (tid & 7) + 24, 64);
            if (tid < 8) {
                float c  = cst[tid];
                float ig = 1.f / (1.f + expf(-gi));
                float fg = 1.f / (1.f + expf(-gf));
                float og = 1.f / (1.f + expf(-go));
                float cn = fg * c + ig * tanhf(gg);
                float hn = og * tanhf(cn);
                cst[tid] = cn;
                astu(&bufE[(size_t)((t + 1) % 3) * 2048 + 8 * w + tid], packh(tg + 1, hn));
            }
        }
        // no trailing sync: hl/red double-buffered
    }

    // ================= latent: 3 rows per WG (h_4096 tag 4096 lives in bufE[4096%3==1]) =================
    {
        const unsigned tg = 4096u;
        const unsigned* p = bufE + (size_t)2048 + wv * 256 + 4 * lane;
        unsigned a0 = aldu(p), a1 = aldu(p + 1), a2 = aldu(p + 2), a3 = aldu(p + 3);
        for (;;) {
            bool ok = ((a0 >> 16) == tg) & ((a1 >> 16) == tg)
                    & ((a2 >> 16) == tg) & ((a3 >> 16) == tg);
            if (__builtin_expect(__all(ok), 1)) break;
            a0 = aldu(p); a1 = aldu(p + 1); a2 = aldu(p + 2); a3 = aldu(p + 3);
        }
        float4 hv = { unpackh(a0), unpackh(a1), unpackh(a2), unpackh(a3) };
        *(float4*)&hl[0][wv * 256 + 4 * lane] = hv;
        __syncthreads();

        if (wv < 3) {
            int row = 3 * w + wv;
            const float* wr = Wls + (size_t)row * 2048;
            float s = 0.f;
            #pragma unroll
            for (int q = 0; q < 32; q++) s += wr[lane + 64 * q] * hl[0][lane + 64 * q];
            for (int o = 32; o; o >>= 1) s += __shfl_xor(s, o, 64);
            if (lane == 0) {
                float lv = tanhf(s + bls[row]);
                out[128 + row] = lv;
                astu(&bufD[128 + row], packh(0u, lv));
            }
        }
        __syncthreads();   // hl[0] reads done before decoder s=1 re-stages hl[0]
    }

    // ---- decoder weights: wave wv owns rows {2wv, 2wv+1} of the WG's 16 rows.
    //      Row r: gate = r>>2, h-slot = r&3 -> global row (r>>2)*1024 + 4w + (r&3).
    float wd[32];
    #pragma unroll
    for (int rr = 0; rr < 2; rr++) {
        int r = wv * 2 + rr;
        const float* src = wsum + (size_t)((r >> 2) * 1024 + 4 * w + (r & 3)) * 1024 + lane;
        #pragma unroll
        for (int j = 0; j < 16; j++) wd[rr * 16 + j] = src[64 * j];
    }
    float bdv = 0.f, pgv = 0.f;
    if (tid < 16) {
        int R = (tid >> 2) * 1024 + 4 * w + (tid & 3);
        bdv = bih_d[R] + bhh_d[R];
        pgv = pg[R];
    }
    if (tid < 8) cst[tid] = 0.f;
    if (tid < 4) {   // c0 = latent_cat[4w+tid]: poll tag 0
        const unsigned* pc = bufD + 4 * w + tid;
        unsigned v;
        do { v = aldu(pc); } while ((v >> 16) != 0u);
        cst[tid] = unpackh(v);
    }
    __syncthreads();

    // ================= decoder: 4094 steps =================
    #pragma unroll 1
    for (int s = 1; s <= 4094; s++) {
        const unsigned tg = (unsigned)(s - 1);
        const unsigned* p = bufD + (size_t)((s - 1) % 3) * 1024 + wv * 128 + 2 * lane;
        unsigned a0 = aldu(p), a1 = aldu(p + 1);
        for (;;) {
            bool ok = ((a0 >> 16) == tg) & ((a1 >> 16) == tg);
            if (__builtin_expect(__all(ok), 1)) break;
            a0 = aldu(p); a1 = aldu(p + 1);
        }
        float2 hv = { unpackh(a0), unpackh(a1) };
        *(float2*)&hl[(s - 1) & 1][wv * 128 + 2 * lane] = hv;
        __syncthreads();

        float s0 = 0.f, s1 = 0.f;
        const float* hp = hl[(s - 1) & 1];
        if (s == 1) {
            // step 1 uses W_hh_dec alone (input term for emb[X] is folded into pg)
            #pragma unroll
            for (int rr = 0; rr < 2; rr++) {
                int r = wv * 2 + rr;
                const float* srcw = Whh_d + (size_t)((r >> 2) * 1024 + 4 * w + (r & 3)) * 1024 + lane;
                float a = 0.f;
                #pragma unroll
                for (int j = 0; j < 16; j++) a += srcw[64 * j] * hp[lane + 64 * j];
                if (rr) s1 = a; else s0 = a;
            }
        } else {
            #pragma unroll
            for (int j = 0; j < 16; j++) {
                float h = hp[lane + 64 * j];
                s0 += wd[j] * h;
                s1 += wd[16 + j] * h;
            }
        }
        #pragma unroll
        for (int o = 32; o; o >>= 1) {
            s0 += __shfl_xor(s0, o, 64);
            s1 += __shfl_xor(s1, o, 64);
        }
        if (lane == 0) { red[(s - 1) & 1][wv * 2] = s0; red[(s - 1) & 1][wv * 2 + 1] = s1; }
        __syncthreads();

        if (tid < 16) {
            float g = red[(s - 1) & 1][tid] + ((s == 1) ? pgv : bdv);
            float gi = __shfl(g, (tid & 3), 64);
            float gf = __shfl(g, (tid & 3) + 4, 64);
            float gg = __shfl(g, (tid & 3) + 8, 64);
            float go = __shfl(g, (tid & 3) + 12, 64);
            if (tid < 4) {
                float c  = cst[tid];
                float ig = 1.f / (1.f + expf(-gi));
                float fg = 1.f / (1.f + expf(-gf));
                float og = 1.f / (1.f + expf(-go));
                float cn = fg * c + ig * tanhf(gg);
                float hn = og * tanhf(cn);
                cst[tid] = cn;
                out[1024 + (size_t)(4095 - s) * 1024 + 4 * w + tid] = hn;
                astu(&bufD[(size_t)(s % 3) * 1024 + 4 * w + tid], packh((unsigned)s, hn));
            }
        }
        // no trailing sync: hl/red double-buffered
    }
}

// ---------------- host launcher ----------------
extern "C" void kernel_launch(void* const* d_in, const int* in_sizes, int n_in,
                              void* d_out, int out_size, void* d_ws, size_t ws_size,
                              hipStream_t stream)
{
    const int* x      = (const int*)d_in[0];
    const int* Vg     = (const int*)d_in[1];
    const int* Jg     = (const int*)d_in[2];
    const float* emb   = (const float*)d_in[4];
    const float* embV  = (const float*)d_in[5];
    const float* embJ  = (const float*)d_in[6];
    const float* Wih_e = (const float*)d_in[7];
    const float* Whh_e = (const float*)d_in[8];
    const float* bih_e = (const float*)d_in[9];
    const float* bhh_e = (const float*)d_in[10];
    const float* Wls   = (const float*)d_in[11];
    const float* bls   = (const float*)d_in[12];
    const float* Wih_d = (const float*)d_in[13];
    const float* Whh_d = (const float*)d_in[14];
    const float* bih_d = (const float*)d_in[15];
    const float* bhh_d = (const float*)d_in[16];
    float* out = (float*)d_out;

    char* ws = (char*)d_ws;
    unsigned* bufE = (unsigned*)ws;             // [3][2048] u32 -> 24576 B
    unsigned* bufD = (unsigned*)(ws + 24576);   // [3][1024] u32 -> 12288 B (ends 36864)
    float* pg   = (float*)(ws + 36864);         // [4096] -> 16384 B (ends 53248)
    short* Abf  = (short*)(ws + 90368);         // [4096*1024]
    short* Wbf  = (short*)(ws + 8478976);       // [8192*1024]
    float* wsum = (float*)(ws + 25256192);      // [4096*1024]
    float* Gx   = (float*)(ws + 42033408);      // [4096][8192]  (total 176,251,136 B)

    prep_all<<<1024, 256, 0, stream>>>(x, Vg, Jg, emb, embV, embJ,
                                       Wih_e, Wih_d, Whh_d,
                                       out, Abf, Wbf, wsum, bufE, bufD);
    prep_pg<<<64, 256, 0, stream>>>(Wih_d, emb, bih_d, bhh_d, pg);
    gemm_xgates<<<2048, 256, 0, stream>>>(Abf, Wbf, bih_e, bhh_e, Gx);

    void* args[] = { (void*)&Whh_e, (void*)&Wls, (void*)&bls, (void*)&Whh_d,
                     (void*)&Gx, (void*)&wsum, (void*)&bih_d, (void*)&bhh_d, (void*)&pg,
                     (void*)&bufE, (void*)&bufD, (void*)&out };
    hipLaunchCooperativeKernel((const void*)rnn_seq, dim3(NWG), dim3(512), args, 0, stream);
}